// Round 9
// baseline (345.173 us; speedup 1.0000x reference)
//
#include <hip/hip_runtime.h>
#include <hip/hip_bf16.h>

typedef unsigned short u16;
typedef __bf16 bf16x8 __attribute__((ext_vector_type(8)));
typedef float f32x4 __attribute__((ext_vector_type(4)));

#define D_MODEL 1024
#define NH 16
#define HD 64
#define SEQ 2048
#define BATCH 2

__device__ __forceinline__ f32x4 mfma16(bf16x8 a, bf16x8 b, f32x4 c) {
    return __builtin_amdgcn_mfma_f32_16x16x32_bf16(a, b, c, 0, 0, 0);
}

__device__ __forceinline__ u16 f2bf(float f) {
    __hip_bfloat16 h = __float2bfloat16(f);
    return *reinterpret_cast<u16*>(&h);
}

// Pack 2 f32 -> 2 bf16 (RNE) in one VALU op.  lo -> bits [15:0], hi -> [31:16].
__device__ __forceinline__ unsigned cvt_pk_bf16(float lo, float hi) {
    unsigned r;
    asm("v_cvt_pk_bf16_f32 %0, %1, %2" : "=v"(r) : "v"(lo), "v"(hi));
    return r;
}

__device__ __forceinline__ void gload_lds16(const void* g, void* l) {
    __builtin_amdgcn_global_load_lds((__attribute__((address_space(1))) void*)g,
                                     (__attribute__((address_space(3))) void*)l,
                                     16, 0, 0);
}

// ---------------------------------------------------------------------------
// Fused prep kernel: one launch = 2x convert + 3x transposeW + maskflags.
// Flat grid 5888 = [0,4096) convert | [4096,4864) transpose | rest maskflags.
// ---------------------------------------------------------------------------
__global__ __launch_bounds__(256) void prep_k(
    const float* __restrict__ X0, const float* __restrict__ X1,
    u16* __restrict__ Xqc, u16* __restrict__ Xkvc,
    const float* __restrict__ W0, const float* __restrict__ W1,
    const float* __restrict__ W2, u16* __restrict__ Wt,
    const int* __restrict__ mask, int* __restrict__ flags) {
    __shared__ __align__(16) u16 t[64][72];
    const int tid = threadIdx.x;
    int bid = blockIdx.x;

    if (bid < 4096) {
        int i = bid * 256 + tid;
        const float* src = X0; u16* dst = Xqc;
        if (i >= 524288) { src = X1; dst = Xkvc; i -= 524288; }
        const float4 a = ((const float4*)src)[i * 2];
        const float4 b = ((const float4*)src)[i * 2 + 1];
        union { u16 h[8]; uint4 v; } u;
        u.h[0] = f2bf(a.x); u.h[1] = f2bf(a.y); u.h[2] = f2bf(a.z); u.h[3] = f2bf(a.w);
        u.h[4] = f2bf(b.x); u.h[5] = f2bf(b.y); u.h[6] = f2bf(b.z); u.h[7] = f2bf(b.w);
        *(uint4*)(dst + i * 8) = u.v;
        return;
    }
    bid -= 4096;
    if (bid < 768) {
        const int z = bid >> 8, rem = bid & 255;
        const int bx = rem & 15, by = rem >> 4;
        const float* src = (z == 0) ? W0 : (z == 1 ? W1 : W2);
        u16* dst = Wt + (size_t)z * D_MODEL * D_MODEL;
        const int r0 = by * 64, c0 = bx * 64;
#pragma unroll
        for (int j = 0; j < 2; ++j) {
            int idx = j * 256 + tid;
            int rr = idx >> 3, cc = idx & 7;
            size_t base = (size_t)(r0 + rr) * D_MODEL + c0 + cc * 8;
            float4 a = *(const float4*)(src + base);
            float4 b = *(const float4*)(src + base + 4);
            union { u16 h[8]; uint4 v; } u;
            u.h[0] = f2bf(a.x); u.h[1] = f2bf(a.y); u.h[2] = f2bf(a.z); u.h[3] = f2bf(a.w);
            u.h[4] = f2bf(b.x); u.h[5] = f2bf(b.y); u.h[6] = f2bf(b.z); u.h[7] = f2bf(b.w);
            *(uint4*)&t[rr][cc * 8] = u.v;
        }
        __syncthreads();
#pragma unroll
        for (int j = 0; j < 2; ++j) {
            int idx = j * 256 + tid;
            int cc = idx >> 3, rr8 = idx & 7;
            union { u16 h[8]; uint4 v; } u;
#pragma unroll
            for (int e = 0; e < 8; ++e) u.h[e] = t[rr8 * 8 + e][cc];
            *(uint4*)(dst + (size_t)(c0 + cc) * D_MODEL + r0 + rr8 * 8) = u.v;
        }
        return;
    }
    bid -= 768;
    {
        const int ti = bid & 31, fi = (bid >> 5) & 15, b = bid >> 9;
        const int f = fi * 128 + (tid >> 1);
        const int4* p = (const int4*)(mask + ((size_t)(b * SEQ + f)) * SEQ + ti * 64 + (tid & 1) * 32);
        int ok = 1;
#pragma unroll
        for (int j = 0; j < 8; ++j) {
            int4 v = p[j];
            ok &= (v.x == 1) & (v.y == 1) & (v.z == 1) & (v.w == 1);
        }
        __shared__ int sflag;
        if (tid == 0) sflag = 1;
        __syncthreads();
        if (!ok) sflag = 0;   // benign race: all writers store 0
        __syncthreads();
        if (tid == 0) flags[(b * 16 + fi) * 32 + ti] = sflag;
    }
}

// ---------------------------------------------------------------------------
// Fused QKV projection GEMM (m97 structure), bf16 in/out.  z=0: Q pre-scaled
// by 0.125*log2e; z=1: K; z=2: V written per-head TRANSPOSED ([b,n,h,t]).
// grid (32, 8, 3), block 256.  R8 XCD-aware remap (kept).
// ---------------------------------------------------------------------------
__global__ __launch_bounds__(256, 3) void qkv_gemm_k(
    const u16* __restrict__ Xq, const u16* __restrict__ Xkv,
    const u16* __restrict__ Wt,
    const float* __restrict__ bq, const float* __restrict__ bk,
    const float* __restrict__ bv,
    u16* __restrict__ Qb, u16* __restrict__ Kb, u16* __restrict__ Vt) {
    const int lbid = (int)blockIdx.x + 32 * (int)blockIdx.y + 256 * (int)blockIdx.z;
    const int xcd = lbid & 7, j = lbid >> 3;
    const int g = xcd * 3 + (j >> 5);
    const int bx = j & 31, by = g & 7, bz = g >> 3;

    const int z = bz;
    const u16* X = (z == 0) ? Xq : Xkv;
    const u16* Wz = Wt + (size_t)z * D_MODEL * D_MODEL;
    const float* bias = (z == 0) ? bq : (z == 1 ? bk : bv);
    const float scale = (z == 0) ? 0.1803368801111244f : 1.0f;  // 0.125*log2(e)

    __shared__ __align__(16) u16 As[128 * 32];
    __shared__ __align__(16) u16 Bs[128 * 32];

    const int tid = threadIdx.x;
    const int w = tid >> 6, lane = tid & 63;
    const int q = lane >> 4, c = lane & 15;
    const int m0 = bx * 128, n0 = by * 128;
    const int mw = (w & 1) * 64, nw = (w >> 1) * 64;

    f32x4 acc[4][4];
    const f32x4 z4 = {0.f, 0.f, 0.f, 0.f};
#pragma unroll
    for (int mi = 0; mi < 4; ++mi)
#pragma unroll
        for (int ni = 0; ni < 4; ++ni) acc[mi][ni] = z4;

    for (int kb = 0; kb < 32; ++kb) {
        const int k0 = kb * 32;
#pragma unroll
        for (int jj = 0; jj < 2; ++jj) {
            int i = jj * 256 + tid;
            int r = i >> 2, cc = i & 3;
            gload_lds16(X + (size_t)(m0 + r) * D_MODEL + k0 + cc * 8, As + i * 8);
            gload_lds16(Wz + (size_t)(n0 + r) * D_MODEL + k0 + cc * 8, Bs + i * 8);
        }
        __syncthreads();
        bf16x8 af[4], bfr[4];
#pragma unroll
        for (int mi = 0; mi < 4; ++mi)
            af[mi] = *(const bf16x8*)(As + (mw + mi * 16 + c) * 32 + q * 8);
#pragma unroll
        for (int ni = 0; ni < 4; ++ni)
            bfr[ni] = *(const bf16x8*)(Bs + (nw + ni * 16 + c) * 32 + q * 8);
#pragma unroll
        for (int mi = 0; mi < 4; ++mi)
#pragma unroll
            for (int ni = 0; ni < 4; ++ni)
                acc[mi][ni] = mfma16(af[mi], bfr[ni], acc[mi][ni]);
        __syncthreads();
    }

    if (z == 2) {
#pragma unroll
        for (int ni = 0; ni < 4; ++ni) {
            const int colg = n0 + nw + ni * 16 + c;
            const float bvv = bias[colg];
            const int head = colg >> 6, h = colg & 63;
#pragma unroll
            for (int mi = 0; mi < 4; ++mi) {
                const int rowg = m0 + mw + mi * 16 + q * 4;
                const int b = rowg >> 11, s = rowg & 2047;
                union { u16 h4[4]; uint2 v2; } pk;
#pragma unroll
                for (int r = 0; r < 4; ++r) pk.h4[r] = f2bf(acc[mi][ni][r] + bvv);
                *(uint2*)(Vt + (((size_t)(b * NH + head)) * HD + h) * SEQ + s) = pk.v2;
            }
        }
    } else {
        u16* outb = (z == 0) ? Qb : Kb;
#pragma unroll
        for (int ni = 0; ni < 4; ++ni) {
            const int colg = n0 + nw + ni * 16 + c;
            const float bvv = bias[colg];
            const int head = colg >> 6, h = colg & 63;
#pragma unroll
            for (int mi = 0; mi < 4; ++mi) {
                const int rowg = m0 + mw + mi * 16 + q * 4;
#pragma unroll
                for (int r = 0; r < 4; ++r) {
                    const int mrow = rowg + r;
                    const int b = mrow >> 11, s = mrow & 2047;
                    const float val = (acc[mi][ni][r] + bvv) * scale;
                    outb[(((size_t)(b * NH + head)) * SEQ + s) * HD + h] = f2bf(val);
                }
            }
        }
    }
}

// ---------------------------------------------------------------------------
// Flash attention, f32 partial outputs.  t-split + setprio + sP swizzle +
// fixed-M-in-accumulator + XCD remap (all kept).
//
// R9: the per-CU LDS pipe was the wall (~112 KB LDS traffic per block-iter
// ~= the 1200-cyc wall; all 4 waves re-read IDENTICAL K/V fragments from
// LDS).  K and V fragments are now loaded DIRECTLY from global (16B/lane,
// L2-resident after the R8 XCD pinning; FETCH_SIZE proved it).  sK/sV are
// gone: LDS = sQ (read-only after stage) + wave-private sP only ->
// NO __syncthreads in the main loop.  V loads issue at iteration top and
// are consumed after softmax (latency self-hiding).  LDS 16 KB/block.
// ---------------------------------------------------------------------------
#define SWZ(row, off) ((off) ^ (((row) & 7) << 3))   // u16 units
#define SMEM_BYTES (128 * 128)              // sQ: 128 rows x 64 u16 (128 B)

__global__ __launch_bounds__(256, 4) void attn_k(
    const u16* __restrict__ Qb, const u16* __restrict__ Kb, const u16* __restrict__ Vt,
    const int* __restrict__ flags, const int* __restrict__ mask,
    float* __restrict__ O0, float* __restrict__ l0, float* __restrict__ l1,
    float* __restrict__ out) {
    __shared__ __align__(16) unsigned char smem[SMEM_BYTES];
    const int tid = threadIdx.x;
    const int w = tid >> 6, lane = tid & 63;
    const int q = lane >> 4, c = lane & 15;
    // XCD remap (R8, bijective): groups of 16 fi-blocks pin to one XCD.
    const int lbid = (int)blockIdx.x + 16 * ((int)blockIdx.y + 32 * (int)blockIdx.z);
    const int xcd = lbid & 7, jj = lbid >> 3;
    const int group = xcd * 8 + (jj >> 4);
    const int fi = jj & 15, bn = group & 31, ts = group >> 5;
    const int b = bn >> 4, n = bn & 15;
    const int f0 = fi * 128;

    u16* sQ = (u16*)(smem);
    u16* sP = sQ + w * 32 * 64;   // wave-private; overlays wave's own Q rows

    // Stage Q tile (128 x 64), swizzled rows
#pragma unroll
    for (int j = 0; j < 4; ++j) {
        int i = j * 256 + tid;
        int r = i >> 3, cc = i & 7;
        uint4 v = *(const uint4*)(Qb + ((size_t)(bn * SEQ + f0 + r)) * HD + cc * 8);
        *(uint4*)(sQ + r * 64 + SWZ(r, cc * 8)) = v;
    }
    __syncthreads();

    // Hoist Q B-fragments (rows [32w, 32w+32))
    bf16x8 qf[2][2];
#pragma unroll
    for (int ft = 0; ft < 2; ++ft)
#pragma unroll
        for (int kb = 0; kb < 2; ++kb)
            qf[ft][kb] = *(const bf16x8*)(sQ + (w * 32 + ft * 16 + c) * 64 + SWZ(c, kb * 32 + q * 8));
    // Wave-local: ensure hoist ds_reads complete before sP writes clobber sQ.
    __asm__ __volatile__("" ::: "memory");
    __builtin_amdgcn_s_waitcnt(0xC07F);   // lgkmcnt(0) only
    __asm__ __volatile__("" ::: "memory");

    // All-ones bf16 B-operand for the l-accumulator MFMA
    union { u16 h[8]; bf16x8 v; } one_u;
#pragma unroll
    for (int j = 0; j < 8; ++j) one_u.h[j] = 0x3F80;
    const bf16x8 ones = one_u.v;

    f32x4 O[2][4], accL[2];
    const f32x4 z4 = {0.f, 0.f, 0.f, 0.f};
    const f32x4 m10 = {-10.f, -10.f, -10.f, -10.f};
#pragma unroll
    for (int mi = 0; mi < 2; ++mi) {
        accL[mi] = z4;
#pragma unroll
        for (int hi = 0; hi < 4; ++hi) O[mi][hi] = z4;
    }
    const int* flagp = flags + (b * 16 + fi) * 32;

    const int it0 = ts * 16;
    for (int it = it0; it < it0 + 16; ++it) {
        const int t0 = it * 64;
        // Direct global loads of this tile's K and V fragments (L2-resident).
        // kf: Kb row (t0+mt*16+c), cols q*8(+32): 16B contiguous per lane.
        // vf: Vt row (hi*16+c), cols t0+kb*32+q*8: 16B contiguous per lane.
        uint4 kr0[4], kr1[4], vr0[4], vr1[4];
#pragma unroll
        for (int mt = 0; mt < 4; ++mt) {
            const u16* kp = Kb + ((size_t)(bn * SEQ + t0 + mt * 16 + c)) * HD + q * 8;
            kr0[mt] = *(const uint4*)(kp);
            kr1[mt] = *(const uint4*)(kp + 32);
        }
#pragma unroll
        for (int hi = 0; hi < 4; ++hi) {
            const u16* vp = Vt + ((size_t)(bn * HD + hi * 16 + c)) * SEQ + t0 + q * 8;
            vr0[hi] = *(const uint4*)(vp);
            vr1[hi] = *(const uint4*)(vp + 32);
        }

        const int maskslow = (flagp[it] == 0);

        // Per-mt slice: S^T = K*Q^T (C-init = -10), P = exp2(st) -> sP.
#pragma unroll
        for (int mt = 0; mt < 4; ++mt) {
            const bf16x8 kf0 = *(const bf16x8*)&kr0[mt];
            const bf16x8 kf1 = *(const bf16x8*)&kr1[mt];
            f32x4 st[2];
            __builtin_amdgcn_s_setprio(1);
#pragma unroll
            for (int ft = 0; ft < 2; ++ft) {
                st[ft] = mfma16(kf0, qf[ft][0], m10);
                st[ft] = mfma16(kf1, qf[ft][1], st[ft]);
            }
            __builtin_amdgcn_s_setprio(0);
            if (maskslow) {
#pragma unroll
                for (int ft = 0; ft < 2; ++ft)
#pragma unroll
                    for (int r = 0; r < 4; ++r) {
                        const int fg = f0 + w * 32 + ft * 16 + c;
                        const int tg = t0 + mt * 16 + q * 4 + r;
                        const int mv = mask[((size_t)(b * SEQ + fg)) * SEQ + tg];
                        st[ft][r] += (1.0f - (float)mv) * (-10000.0f) * 1.4426950408889634f;
                    }
            }
#pragma unroll
            for (int ft = 0; ft < 2; ++ft) {
                uint2 v2;
                v2.x = cvt_pk_bf16(exp2f(st[ft][0]), exp2f(st[ft][1]));
                v2.y = cvt_pk_bf16(exp2f(st[ft][2]), exp2f(st[ft][3]));
                *(uint2*)(sP + (ft * 16 + c) * 64 + SWZ(c, mt * 16 + q * 4)) = v2;
            }
        }
        // Wave-local commit of sP writes before sP reads (sP is wave-private).
        __asm__ __volatile__("" ::: "memory");
        __builtin_amdgcn_s_waitcnt(0xC07F);
        __asm__ __volatile__("" ::: "memory");

        // O += P*V ; accL += P*1   (V operand straight from registers)
        __builtin_amdgcn_s_setprio(1);
#pragma unroll
        for (int kb = 0; kb < 2; ++kb) {
            bf16x8 pf0 = *(const bf16x8*)(sP + (0 * 16 + c) * 64 + SWZ(c, kb * 32 + q * 8));
            bf16x8 pf1 = *(const bf16x8*)(sP + (1 * 16 + c) * 64 + SWZ(c, kb * 32 + q * 8));
#pragma unroll
            for (int hi = 0; hi < 4; ++hi) {
                const bf16x8 vf = kb ? *(const bf16x8*)&vr1[hi]
                                     : *(const bf16x8*)&vr0[hi];
                O[0][hi] = mfma16(pf0, vf, O[0][hi]);
                O[1][hi] = mfma16(pf1, vf, O[1][hi]);
            }
            accL[0] = mfma16(pf0, ones, accL[0]);
            accL[1] = mfma16(pf1, ones, accL[1]);
        }
        __builtin_amdgcn_s_setprio(0);
        // Wave-local WAR guard: this iter's sP ds_reads must retire before
        // next iter's sP writes (DS pipe is per-wave in-order; this is
        // belt-and-braces and nearly free -- reads are already awaited).
        __asm__ __volatile__("" ::: "memory");
        __builtin_amdgcn_s_waitcnt(0xC07F);
        __asm__ __volatile__("" ::: "memory");
    }

    // Store un-normalized partial O and partial l.
    float* Odst = ts ? out : O0;
    float* ldst = ts ? l1 : l0;
#pragma unroll
    for (int mi = 0; mi < 2; ++mi)
#pragma unroll
        for (int hi = 0; hi < 4; ++hi)
#pragma unroll
            for (int r = 0; r < 4; ++r) {
                const int fg = f0 + w * 32 + mi * 16 + q * 4 + r;
                const int col = n * 64 + hi * 16 + c;
                Odst[((size_t)(b * SEQ + fg)) * D_MODEL + col] = O[mi][hi][r];
            }
    if (c == 0) {
#pragma unroll
        for (int mi = 0; mi < 2; ++mi)
#pragma unroll
            for (int r = 0; r < 4; ++r) {
                const int fg = f0 + w * 32 + mi * 16 + q * 4 + r;
                ldst[(size_t)bn * SEQ + fg] = accL[mi][r];
            }
    }
}

// ---------------------------------------------------------------------------
// Combine: out = (O0 + out) / (l0 + l1).  float4/thread, grid 4096 x 256.
// ---------------------------------------------------------------------------
__global__ __launch_bounds__(256) void combine_k(const float* __restrict__ O0,
                                                 const float* __restrict__ l0,
                                                 const float* __restrict__ l1,
                                                 float* __restrict__ out) {
    const int i = blockIdx.x * 256 + threadIdx.x;   // float4 index
    const int bf = i >> 8;                          // b*SEQ + f
    const int col = (i & 255) << 2;                 // 0..1020
    const int n = col >> 6;
    const int lidx = ((bf >> 11) * NH + n) * SEQ + (bf & (SEQ - 1));
    const float inv = 1.0f / (l0[lidx] + l1[lidx]);
    const float4 a = ((const float4*)O0)[i];
    const float4 cpart = ((const float4*)out)[i];
    float4 r;
    r.x = (a.x + cpart.x) * inv;
    r.y = (a.y + cpart.y) * inv;
    r.z = (a.z + cpart.z) * inv;
    r.w = (a.w + cpart.w) * inv;
    ((float4*)out)[i] = r;
}

// ---------------------------------------------------------------------------
__global__ __launch_bounds__(256) void signal_k(float* __restrict__ out, int n,
                                                float val) {
    const int i = blockIdx.x * 256 + threadIdx.x;
    if (i < n) out[i] = val;
}

// ---------------------------------------------------------------------------
extern "C" void kernel_launch(void* const* d_in, const int* in_sizes, int n_in,
                              void* d_out, int out_size, void* d_ws, size_t ws_size,
                              hipStream_t stream) {
    const float* Xs[2] = {nullptr, nullptr};
    const float* Wp[3] = {nullptr, nullptr, nullptr};
    const float* Bp[3] = {nullptr, nullptr, nullptr};
    const int* mask = nullptr;
    int nx = 0, nw = 0, nb = 0;
    for (int i = 0; i < n_in; ++i) {
        const long long sz = in_sizes[i];
        if (sz == (long long)BATCH * SEQ * D_MODEL) {
            if (nx < 2) Xs[nx++] = (const float*)d_in[i];
        } else if (sz == (long long)BATCH * SEQ * SEQ) {
            mask = (const int*)d_in[i];
        } else if (sz == (long long)D_MODEL * D_MODEL) {
            if (nw < 3) Wp[nw++] = (const float*)d_in[i];
        } else if (sz == (long long)D_MODEL) {
            if (nb < 3) Bp[nb++] = (const float*)d_in[i];
        }
    }
    float* outp = (float*)d_out;
    const size_t MB = 1024 * 1024;
    const size_t NEED = 47 * MB;

    if (ws_size < NEED || nx != 2 || nw != 3 || nb != 3 || !mask) {
        float code = 1000.0f + (float)(ws_size / MB)
                   + (nx != 2 ? 10000.0f : 0.f)
                   + (nw != 3 ? 20000.0f : 0.f)
                   + (nb != 3 ? 40000.0f : 0.f)
                   + (!mask   ? 80000.0f : 0.f);
        signal_k<<<(out_size + 255) / 256, 256, 0, stream>>>(outp, out_size, code);
        return;
    }

    char* ws = (char*)d_ws;
    u16* Xqc   = (u16*)(ws);              // 8 MB bf16 from_tensor
    u16* Xkvc  = (u16*)(ws + 8 * MB);     // 8 MB bf16 to_tensor
    u16* Wt    = (u16*)(ws + 16 * MB);    // 6 MB: 3 transposed bf16 W slabs
    u16* Qb    = (u16*)(ws + 22 * MB);    // 8 MB [b,n,s,h] (pre-scaled)
    u16* Kb    = (u16*)(ws + 30 * MB);    // 8 MB [b,n,t,h]
    u16* Vt    = (u16*)(ws + 38 * MB);    // 8 MB [b,n,h,t]
    int* flags = (int*)(ws + 46 * MB);    // 4 KB
    // t-split partials: O0 overlays Xqc+Xkvc (dead after qkv_gemm);
    // l0/l1 live after flags in the 46..47 MB slab.
    float* O0 = (float*)(ws);                                   // 16 MB
    float* l0 = (float*)(ws + 46 * MB + 16 * 1024);             // 256 KB
    float* l1 = (float*)(ws + 46 * MB + 16 * 1024 + 256 * 1024);// 256 KB

    prep_k<<<5888, 256, 0, stream>>>(Xs[0], Xs[1], Xqc, Xkvc,
                                     Wp[0], Wp[1], Wp[2], Wt, mask, flags);
    qkv_gemm_k<<<dim3(32, 8, 3), 256, 0, stream>>>(Xqc, Xkvc, Wt,
                                                   Bp[0], Bp[1], Bp[2], Qb, Kb, Vt);
    attn_k<<<dim3(16, 32, 2), 256, 0, stream>>>(Qb, Kb, Vt, flags, mask,
                                                O0, l0, l1, outp);
    combine_k<<<4096, 256, 0, stream>>>(O0, l0, l1, outp);
}

// Round 10
// 221.466 us; speedup vs baseline: 1.5586x; 1.5586x over previous
//
#include <hip/hip_runtime.h>
#include <hip/hip_bf16.h>

typedef unsigned short u16;
typedef __bf16 bf16x8 __attribute__((ext_vector_type(8)));
typedef float f32x4 __attribute__((ext_vector_type(4)));

#define D_MODEL 1024
#define NH 16
#define HD 64
#define SEQ 2048
#define BATCH 2

__device__ __forceinline__ f32x4 mfma16(bf16x8 a, bf16x8 b, f32x4 c) {
    return __builtin_amdgcn_mfma_f32_16x16x32_bf16(a, b, c, 0, 0, 0);
}

__device__ __forceinline__ u16 f2bf(float f) {
    __hip_bfloat16 h = __float2bfloat16(f);
    return *reinterpret_cast<u16*>(&h);
}

// Pack 2 f32 -> 2 bf16 (RNE) in one VALU op.  lo -> bits [15:0], hi -> [31:16].
__device__ __forceinline__ unsigned cvt_pk_bf16(float lo, float hi) {
    unsigned r;
    asm("v_cvt_pk_bf16_f32 %0, %1, %2" : "=v"(r) : "v"(lo), "v"(hi));
    return r;
}

__device__ __forceinline__ void gload_lds16(const void* g, void* l) {
    __builtin_amdgcn_global_load_lds((__attribute__((address_space(1))) void*)g,
                                     (__attribute__((address_space(3))) void*)l,
                                     16, 0, 0);
}

// ---------------------------------------------------------------------------
// Fused prep kernel: one launch = 2x convert + 3x transposeW + maskflags.
// Flat grid 5888 = [0,4096) convert | [4096,4864) transpose | rest maskflags.
// ---------------------------------------------------------------------------
__global__ __launch_bounds__(256) void prep_k(
    const float* __restrict__ X0, const float* __restrict__ X1,
    u16* __restrict__ Xqc, u16* __restrict__ Xkvc,
    const float* __restrict__ W0, const float* __restrict__ W1,
    const float* __restrict__ W2, u16* __restrict__ Wt,
    const int* __restrict__ mask, int* __restrict__ flags) {
    __shared__ __align__(16) u16 t[64][72];
    const int tid = threadIdx.x;
    int bid = blockIdx.x;

    if (bid < 4096) {
        int i = bid * 256 + tid;
        const float* src = X0; u16* dst = Xqc;
        if (i >= 524288) { src = X1; dst = Xkvc; i -= 524288; }
        const float4 a = ((const float4*)src)[i * 2];
        const float4 b = ((const float4*)src)[i * 2 + 1];
        union { u16 h[8]; uint4 v; } u;
        u.h[0] = f2bf(a.x); u.h[1] = f2bf(a.y); u.h[2] = f2bf(a.z); u.h[3] = f2bf(a.w);
        u.h[4] = f2bf(b.x); u.h[5] = f2bf(b.y); u.h[6] = f2bf(b.z); u.h[7] = f2bf(b.w);
        *(uint4*)(dst + i * 8) = u.v;
        return;
    }
    bid -= 4096;
    if (bid < 768) {
        const int z = bid >> 8, rem = bid & 255;
        const int bx = rem & 15, by = rem >> 4;
        const float* src = (z == 0) ? W0 : (z == 1 ? W1 : W2);
        u16* dst = Wt + (size_t)z * D_MODEL * D_MODEL;
        const int r0 = by * 64, c0 = bx * 64;
#pragma unroll
        for (int j = 0; j < 2; ++j) {
            int idx = j * 256 + tid;
            int rr = idx >> 3, cc = idx & 7;
            size_t base = (size_t)(r0 + rr) * D_MODEL + c0 + cc * 8;
            float4 a = *(const float4*)(src + base);
            float4 b = *(const float4*)(src + base + 4);
            union { u16 h[8]; uint4 v; } u;
            u.h[0] = f2bf(a.x); u.h[1] = f2bf(a.y); u.h[2] = f2bf(a.z); u.h[3] = f2bf(a.w);
            u.h[4] = f2bf(b.x); u.h[5] = f2bf(b.y); u.h[6] = f2bf(b.z); u.h[7] = f2bf(b.w);
            *(uint4*)&t[rr][cc * 8] = u.v;
        }
        __syncthreads();
#pragma unroll
        for (int j = 0; j < 2; ++j) {
            int idx = j * 256 + tid;
            int cc = idx >> 3, rr8 = idx & 7;
            union { u16 h[8]; uint4 v; } u;
#pragma unroll
            for (int e = 0; e < 8; ++e) u.h[e] = t[rr8 * 8 + e][cc];
            *(uint4*)(dst + (size_t)(c0 + cc) * D_MODEL + r0 + rr8 * 8) = u.v;
        }
        return;
    }
    bid -= 768;
    {
        const int ti = bid & 31, fi = (bid >> 5) & 15, b = bid >> 9;
        const int f = fi * 128 + (tid >> 1);
        const int4* p = (const int4*)(mask + ((size_t)(b * SEQ + f)) * SEQ + ti * 64 + (tid & 1) * 32);
        int ok = 1;
#pragma unroll
        for (int j = 0; j < 8; ++j) {
            int4 v = p[j];
            ok &= (v.x == 1) & (v.y == 1) & (v.z == 1) & (v.w == 1);
        }
        __shared__ int sflag;
        if (tid == 0) sflag = 1;
        __syncthreads();
        if (!ok) sflag = 0;   // benign race: all writers store 0
        __syncthreads();
        if (tid == 0) flags[(b * 16 + fi) * 32 + ti] = sflag;
    }
}

// ---------------------------------------------------------------------------
// Fused QKV projection GEMM (m97 structure), bf16 in/out.  z=0: Q pre-scaled
// by 0.125*log2e; z=1: K; z=2: V written per-head TRANSPOSED ([b,n,h,t]).
// grid (32, 8, 3), block 256.  XCD-aware remap: each XCD owns 3 complete
// (n0,z) panel-groups -> W panel stays hot in one L2.
// ---------------------------------------------------------------------------
__global__ __launch_bounds__(256, 3) void qkv_gemm_k(
    const u16* __restrict__ Xq, const u16* __restrict__ Xkv,
    const u16* __restrict__ Wt,
    const float* __restrict__ bq, const float* __restrict__ bk,
    const float* __restrict__ bv,
    u16* __restrict__ Qb, u16* __restrict__ Kb, u16* __restrict__ Vt) {
    const int lbid = (int)blockIdx.x + 32 * (int)blockIdx.y + 256 * (int)blockIdx.z;
    const int xcd = lbid & 7, j = lbid >> 3;
    const int g = xcd * 3 + (j >> 5);
    const int bx = j & 31, by = g & 7, bz = g >> 3;

    const int z = bz;
    const u16* X = (z == 0) ? Xq : Xkv;
    const u16* Wz = Wt + (size_t)z * D_MODEL * D_MODEL;
    const float* bias = (z == 0) ? bq : (z == 1 ? bk : bv);
    const float scale = (z == 0) ? 0.1803368801111244f : 1.0f;  // 0.125*log2(e)

    __shared__ __align__(16) u16 As[128 * 32];
    __shared__ __align__(16) u16 Bs[128 * 32];

    const int tid = threadIdx.x;
    const int w = tid >> 6, lane = tid & 63;
    const int q = lane >> 4, c = lane & 15;
    const int m0 = bx * 128, n0 = by * 128;
    const int mw = (w & 1) * 64, nw = (w >> 1) * 64;

    f32x4 acc[4][4];
    const f32x4 z4 = {0.f, 0.f, 0.f, 0.f};
#pragma unroll
    for (int mi = 0; mi < 4; ++mi)
#pragma unroll
        for (int ni = 0; ni < 4; ++ni) acc[mi][ni] = z4;

    for (int kb = 0; kb < 32; ++kb) {
        const int k0 = kb * 32;
#pragma unroll
        for (int jj = 0; jj < 2; ++jj) {
            int i = jj * 256 + tid;
            int r = i >> 2, cc = i & 3;
            gload_lds16(X + (size_t)(m0 + r) * D_MODEL + k0 + cc * 8, As + i * 8);
            gload_lds16(Wz + (size_t)(n0 + r) * D_MODEL + k0 + cc * 8, Bs + i * 8);
        }
        __syncthreads();
        bf16x8 af[4], bfr[4];
#pragma unroll
        for (int mi = 0; mi < 4; ++mi)
            af[mi] = *(const bf16x8*)(As + (mw + mi * 16 + c) * 32 + q * 8);
#pragma unroll
        for (int ni = 0; ni < 4; ++ni)
            bfr[ni] = *(const bf16x8*)(Bs + (nw + ni * 16 + c) * 32 + q * 8);
#pragma unroll
        for (int mi = 0; mi < 4; ++mi)
#pragma unroll
            for (int ni = 0; ni < 4; ++ni)
                acc[mi][ni] = mfma16(af[mi], bfr[ni], acc[mi][ni]);
        __syncthreads();
    }

    if (z == 2) {
#pragma unroll
        for (int ni = 0; ni < 4; ++ni) {
            const int colg = n0 + nw + ni * 16 + c;
            const float bvv = bias[colg];
            const int head = colg >> 6, h = colg & 63;
#pragma unroll
            for (int mi = 0; mi < 4; ++mi) {
                const int rowg = m0 + mw + mi * 16 + q * 4;
                const int b = rowg >> 11, s = rowg & 2047;
                union { u16 h4[4]; uint2 v2; } pk;
#pragma unroll
                for (int r = 0; r < 4; ++r) pk.h4[r] = f2bf(acc[mi][ni][r] + bvv);
                *(uint2*)(Vt + (((size_t)(b * NH + head)) * HD + h) * SEQ + s) = pk.v2;
            }
        }
    } else {
        u16* outb = (z == 0) ? Qb : Kb;
#pragma unroll
        for (int ni = 0; ni < 4; ++ni) {
            const int colg = n0 + nw + ni * 16 + c;
            const float bvv = bias[colg];
            const int head = colg >> 6, h = colg & 63;
#pragma unroll
            for (int mi = 0; mi < 4; ++mi) {
                const int rowg = m0 + mw + mi * 16 + q * 4;
#pragma unroll
                for (int r = 0; r < 4; ++r) {
                    const int mrow = rowg + r;
                    const int b = mrow >> 11, s = mrow & 2047;
                    const float val = (acc[mi][ni][r] + bvv) * scale;
                    outb[(((size_t)(b * NH + head)) * SEQ + s) * HD + h] = f2bf(val);
                }
            }
        }
    }
}

// ---------------------------------------------------------------------------
// Flash attention, f32 partial outputs.  R4 t-split + R5 setprio + R6 swizzle
// + R7 VALU cuts + R8 XCD remap.  (R9's direct-L2 K/V fragment loads were a
// 3x regression -- uncoalesced 64B gathers + L2 write-thrash; REVERTED to the
// verified LDS-staged form.)
// ---------------------------------------------------------------------------
#define SWZ(row, off) ((off) ^ (((row) & 7) << 3))   // u16 units
#define SK_OFF (128 * 128)                  // bytes: sQ = 128 rows x 128 B
#define SV_OFF (SK_OFF + 64 * 128)
#define SMEM_BYTES (SV_OFF + 64 * 128)      // 32768

__global__ __launch_bounds__(256, 4) void attn_k(
    const u16* __restrict__ Qb, const u16* __restrict__ Kb, const u16* __restrict__ Vt,
    const int* __restrict__ flags, const int* __restrict__ mask,
    float* __restrict__ O0, float* __restrict__ l0, float* __restrict__ l1,
    float* __restrict__ out) {
    __shared__ __align__(16) unsigned char smem[SMEM_BYTES];
    const int tid = threadIdx.x;
    const int w = tid >> 6, lane = tid & 63;
    const int q = lane >> 4, c = lane & 15;
    // XCD remap (bijective): groups of 16 fi-blocks pin to one XCD.
    const int lbid = (int)blockIdx.x + 16 * ((int)blockIdx.y + 32 * (int)blockIdx.z);
    const int xcd = lbid & 7, jj = lbid >> 3;
    const int group = xcd * 8 + (jj >> 4);
    const int fi = jj & 15, bn = group & 31, ts = group >> 5;
    const int b = bn >> 4, n = bn & 15;
    const int f0 = fi * 128;

    u16* sQ = (u16*)(smem);
    u16* sK = (u16*)(smem + SK_OFF);
    u16* sV = (u16*)(smem + SV_OFF);
    u16* sP = sQ + w * 32 * 64;   // wave-private; overlays wave's own Q rows

    // Stage Q tile (128 x 64), swizzled rows
#pragma unroll
    for (int j = 0; j < 4; ++j) {
        int i = j * 256 + tid;
        int r = i >> 3, cc = i & 7;
        uint4 v = *(const uint4*)(Qb + ((size_t)(bn * SEQ + f0 + r)) * HD + cc * 8);
        *(uint4*)(sQ + r * 64 + SWZ(r, cc * 8)) = v;
    }
    __syncthreads();

    // Hoist Q B-fragments (rows [32w, 32w+32))
    bf16x8 qf[2][2];
#pragma unroll
    for (int ft = 0; ft < 2; ++ft)
#pragma unroll
        for (int kb = 0; kb < 2; ++kb)
            qf[ft][kb] = *(const bf16x8*)(sQ + (w * 32 + ft * 16 + c) * 64 + SWZ(c, kb * 32 + q * 8));
    // Wave-local: ensure hoist ds_reads complete before sP writes clobber sQ.
    __asm__ __volatile__("" ::: "memory");
    __builtin_amdgcn_s_waitcnt(0xC07F);   // lgkmcnt(0) only
    __asm__ __volatile__("" ::: "memory");

    // All-ones bf16 B-operand for the l-accumulator MFMA
    union { u16 h[8]; bf16x8 v; } one_u;
#pragma unroll
    for (int j = 0; j < 8; ++j) one_u.h[j] = 0x3F80;
    const bf16x8 ones = one_u.v;

    f32x4 O[2][4], accL[2];
    const f32x4 z4 = {0.f, 0.f, 0.f, 0.f};
    const f32x4 m10 = {-10.f, -10.f, -10.f, -10.f};
#pragma unroll
    for (int mi = 0; mi < 2; ++mi) {
        accL[mi] = z4;
#pragma unroll
        for (int hi = 0; hi < 4; ++hi) O[mi][hi] = z4;
    }
    const int* flagp = flags + (b * 16 + fi) * 32;

    const int it0 = ts * 16;
    for (int it = it0; it < it0 + 16; ++it) {
        const int t0 = it * 64;
        // Stage K (64x64 [t][h]) and V^T (64x64 [h][t]), swizzled rows
#pragma unroll
        for (int j = 0; j < 2; ++j) {
            int i = j * 256 + tid;
            int r = i >> 3, cc = i & 7;
            uint4 kv = *(const uint4*)(Kb + ((size_t)(bn * SEQ + t0 + r)) * HD + cc * 8);
            uint4 vv = *(const uint4*)(Vt + ((size_t)(bn * HD + r)) * SEQ + t0 + cc * 8);
            const int so = r * 64 + SWZ(r, cc * 8);
            *(uint4*)(sK + so) = kv;
            *(uint4*)(sV + so) = vv;
        }
        __syncthreads();

        const int maskslow = (flagp[it] == 0);

        // Per-mt slice: S^T = K*Q^T (C-init = -10), P = exp2(st) -> sP.
#pragma unroll
        for (int mt = 0; mt < 4; ++mt) {
            bf16x8 kf0 = *(const bf16x8*)(sK + (mt * 16 + c) * 64 + SWZ(c, 0 + q * 8));
            bf16x8 kf1 = *(const bf16x8*)(sK + (mt * 16 + c) * 64 + SWZ(c, 32 + q * 8));
            f32x4 st[2];
            __builtin_amdgcn_s_setprio(1);
#pragma unroll
            for (int ft = 0; ft < 2; ++ft) {
                st[ft] = mfma16(kf0, qf[ft][0], m10);
                st[ft] = mfma16(kf1, qf[ft][1], st[ft]);
            }
            __builtin_amdgcn_s_setprio(0);
            if (maskslow) {
#pragma unroll
                for (int ft = 0; ft < 2; ++ft)
#pragma unroll
                    for (int r = 0; r < 4; ++r) {
                        const int fg = f0 + w * 32 + ft * 16 + c;
                        const int tg = t0 + mt * 16 + q * 4 + r;
                        const int mv = mask[((size_t)(b * SEQ + fg)) * SEQ + tg];
                        st[ft][r] += (1.0f - (float)mv) * (-10000.0f) * 1.4426950408889634f;
                    }
            }
#pragma unroll
            for (int ft = 0; ft < 2; ++ft) {
                uint2 v2;
                v2.x = cvt_pk_bf16(exp2f(st[ft][0]), exp2f(st[ft][1]));
                v2.y = cvt_pk_bf16(exp2f(st[ft][2]), exp2f(st[ft][3]));
                *(uint2*)(sP + (ft * 16 + c) * 64 + SWZ(c, mt * 16 + q * 4)) = v2;
            }
        }
        // Wave-local commit of sP writes before sP reads (sP is wave-private).
        __asm__ __volatile__("" ::: "memory");
        __builtin_amdgcn_s_waitcnt(0xC07F);
        __asm__ __volatile__("" ::: "memory");

        // O += P*V ; accL += P*1
        __builtin_amdgcn_s_setprio(1);
#pragma unroll
        for (int kb = 0; kb < 2; ++kb) {
            bf16x8 pf0 = *(const bf16x8*)(sP + (0 * 16 + c) * 64 + SWZ(c, kb * 32 + q * 8));
            bf16x8 pf1 = *(const bf16x8*)(sP + (1 * 16 + c) * 64 + SWZ(c, kb * 32 + q * 8));
#pragma unroll
            for (int hi = 0; hi < 4; ++hi) {
                bf16x8 vf = *(const bf16x8*)(sV + (hi * 16 + c) * 64 + SWZ(c, kb * 32 + q * 8));
                O[0][hi] = mfma16(pf0, vf, O[0][hi]);
                O[1][hi] = mfma16(pf1, vf, O[1][hi]);
            }
            accL[0] = mfma16(pf0, ones, accL[0]);
            accL[1] = mfma16(pf1, ones, accL[1]);
        }
        __builtin_amdgcn_s_setprio(0);
        __syncthreads();   // protect sK/sV restage (next iter) + sP/sQ races
    }

    // Store un-normalized partial O and partial l.
    float* Odst = ts ? out : O0;
    float* ldst = ts ? l1 : l0;
#pragma unroll
    for (int mi = 0; mi < 2; ++mi)
#pragma unroll
        for (int hi = 0; hi < 4; ++hi)
#pragma unroll
            for (int r = 0; r < 4; ++r) {
                const int fg = f0 + w * 32 + mi * 16 + q * 4 + r;
                const int col = n * 64 + hi * 16 + c;
                Odst[((size_t)(b * SEQ + fg)) * D_MODEL + col] = O[mi][hi][r];
            }
    if (c == 0) {
#pragma unroll
        for (int mi = 0; mi < 2; ++mi)
#pragma unroll
            for (int r = 0; r < 4; ++r) {
                const int fg = f0 + w * 32 + mi * 16 + q * 4 + r;
                ldst[(size_t)bn * SEQ + fg] = accL[mi][r];
            }
    }
}

// ---------------------------------------------------------------------------
// Combine: out = (O0 + out) / (l0 + l1).  float4/thread, grid 4096 x 256.
// ---------------------------------------------------------------------------
__global__ __launch_bounds__(256) void combine_k(const float* __restrict__ O0,
                                                 const float* __restrict__ l0,
                                                 const float* __restrict__ l1,
                                                 float* __restrict__ out) {
    const int i = blockIdx.x * 256 + threadIdx.x;   // float4 index
    const int bf = i >> 8;                          // b*SEQ + f
    const int col = (i & 255) << 2;                 // 0..1020
    const int n = col >> 6;
    const int lidx = ((bf >> 11) * NH + n) * SEQ + (bf & (SEQ - 1));
    const float inv = 1.0f / (l0[lidx] + l1[lidx]);
    const float4 a = ((const float4*)O0)[i];
    const float4 cpart = ((const float4*)out)[i];
    float4 r;
    r.x = (a.x + cpart.x) * inv;
    r.y = (a.y + cpart.y) * inv;
    r.z = (a.z + cpart.z) * inv;
    r.w = (a.w + cpart.w) * inv;
    ((float4*)out)[i] = r;
}

// ---------------------------------------------------------------------------
__global__ __launch_bounds__(256) void signal_k(float* __restrict__ out, int n,
                                                float val) {
    const int i = blockIdx.x * 256 + threadIdx.x;
    if (i < n) out[i] = val;
}

// ---------------------------------------------------------------------------
extern "C" void kernel_launch(void* const* d_in, const int* in_sizes, int n_in,
                              void* d_out, int out_size, void* d_ws, size_t ws_size,
                              hipStream_t stream) {
    const float* Xs[2] = {nullptr, nullptr};
    const float* Wp[3] = {nullptr, nullptr, nullptr};
    const float* Bp[3] = {nullptr, nullptr, nullptr};
    const int* mask = nullptr;
    int nx = 0, nw = 0, nb = 0;
    for (int i = 0; i < n_in; ++i) {
        const long long sz = in_sizes[i];
        if (sz == (long long)BATCH * SEQ * D_MODEL) {
            if (nx < 2) Xs[nx++] = (const float*)d_in[i];
        } else if (sz == (long long)BATCH * SEQ * SEQ) {
            mask = (const int*)d_in[i];
        } else if (sz == (long long)D_MODEL * D_MODEL) {
            if (nw < 3) Wp[nw++] = (const float*)d_in[i];
        } else if (sz == (long long)D_MODEL) {
            if (nb < 3) Bp[nb++] = (const float*)d_in[i];
        }
    }
    float* outp = (float*)d_out;
    const size_t MB = 1024 * 1024;
    const size_t NEED = 47 * MB;

    if (ws_size < NEED || nx != 2 || nw != 3 || nb != 3 || !mask) {
        float code = 1000.0f + (float)(ws_size / MB)
                   + (nx != 2 ? 10000.0f : 0.f)
                   + (nw != 3 ? 20000.0f : 0.f)
                   + (nb != 3 ? 40000.0f : 0.f)
                   + (!mask   ? 80000.0f : 0.f);
        signal_k<<<(out_size + 255) / 256, 256, 0, stream>>>(outp, out_size, code);
        return;
    }

    char* ws = (char*)d_ws;
    u16* Xqc   = (u16*)(ws);              // 8 MB bf16 from_tensor
    u16* Xkvc  = (u16*)(ws + 8 * MB);     // 8 MB bf16 to_tensor
    u16* Wt    = (u16*)(ws + 16 * MB);    // 6 MB: 3 transposed bf16 W slabs
    u16* Qb    = (u16*)(ws + 22 * MB);    // 8 MB [b,n,s,h] (pre-scaled)
    u16* Kb    = (u16*)(ws + 30 * MB);    // 8 MB [b,n,t,h]
    u16* Vt    = (u16*)(ws + 38 * MB);    // 8 MB [b,n,h,t]
    int* flags = (int*)(ws + 46 * MB);    // 4 KB
    // t-split partials: O0 overlays Xqc+Xkvc (dead after qkv_gemm);
    // l0/l1 live after flags in the 46..47 MB slab.
    float* O0 = (float*)(ws);                                   // 16 MB
    float* l0 = (float*)(ws + 46 * MB + 16 * 1024);             // 256 KB
    float* l1 = (float*)(ws + 46 * MB + 16 * 1024 + 256 * 1024);// 256 KB

    prep_k<<<5888, 256, 0, stream>>>(Xs[0], Xs[1], Xqc, Xkvc,
                                     Wp[0], Wp[1], Wp[2], Wt, mask, flags);
    qkv_gemm_k<<<dim3(32, 8, 3), 256, 0, stream>>>(Xqc, Xkvc, Wt,
                                                   Bp[0], Bp[1], Bp[2], Qb, Kb, Vt);
    attn_k<<<dim3(16, 32, 2), 256, 0, stream>>>(Qb, Kb, Vt, flags, mask,
                                                O0, l0, l1, outp);
    combine_k<<<4096, 256, 0, stream>>>(O0, l0, l1, outp);
}